// Round 7
// baseline (231.757 us; speedup 1.0000x reference)
//
#include <hip/hip_runtime.h>

typedef _Float16 f16;
typedef _Float16 f16x2 __attribute__((ext_vector_type(2)));
typedef _Float16 f16x4 __attribute__((ext_vector_type(4)));
typedef _Float16 f16x8 __attribute__((ext_vector_type(8)));
typedef float    f32x4 __attribute__((ext_vector_type(4)));

#define B_  2
#define C_  512
#define N_  2048
#define H_  8
#define DK_ 64
#define BH_ 16
#define NIT 8

static __device__ __forceinline__ f16x2 cvt_pk(float a, float b) {
  return __builtin_bit_cast(f16x2, __builtin_amdgcn_cvt_pkrtz(a, b));
}

#if defined(__has_builtin)
#if __has_builtin(__builtin_amdgcn_fdot2)
#define FDOT2(a,b,c) __builtin_amdgcn_fdot2((a),(b),(c),false)
#endif
#endif
#ifndef FDOT2
static __device__ __forceinline__ float FDOT2(f16x2 a, f16x2 b, float c) {
  return c + (float)a[0]*(float)b[0] + (float)a[1]*(float)b[1];
}
#endif

#define MFMA16(a,b,acc) __builtin_amdgcn_mfma_f32_16x16x32_f16((a),(b),(acc),0,0,0)

// ---------------- prep_x: x (b,m,n) fp32 -> xT16 (b,n,m) f16 ------------------
__global__ __launch_bounds__(256) void prep_x(const float* __restrict__ x,
                                              f16* __restrict__ xT)
{
  const int nt = blockIdx.x, mt = blockIdx.y, b = blockIdx.z;
  const int n0 = nt * 64, m0 = mt * 64;
  __shared__ float tile[64][65];
  const int t = threadIdx.x;
  {
    const int ml = t >> 2, nc = (t & 3) * 16;
    const float* src = x + ((size_t)(b * C_ + m0 + ml)) * N_ + n0 + nc;
    *(float4*)&tile[ml][nc]      = *(const float4*)(src);
    *(float4*)&tile[ml][nc + 4]  = *(const float4*)(src + 4);
    *(float4*)&tile[ml][nc + 8]  = *(const float4*)(src + 8);
    *(float4*)&tile[ml][nc + 12] = *(const float4*)(src + 12);
  }
  __syncthreads();
  {
    const int nl = t >> 2, mc = (t & 3) * 16;
    f16x8 o0, o1;
    #pragma unroll
    for (int i = 0; i < 8; ++i) {
      o0[i] = (f16)tile[mc + i][nl];
      o1[i] = (f16)tile[mc + 8 + i][nl];
    }
    f16* dst = xT + ((size_t)(b * N_ + n0 + nl)) * C_ + m0 + mc;
    *(f16x8*)(dst)     = o0;
    *(f16x8*)(dst + 8) = o1;
  }
}

// ---------------- qkv_lds: LDS-staged GEMM, 128n x 64c tile, BK=64 ------------
// A = xT16 (f16), B = W fp32 (cvt in stager). XOR-swizzled LDS (chunk ^= row&7).
// mat 0/1 (Q,K): (b,h,n,d). mat 2 (V): transposed (b,c,n) in PI-order:
//   within each 32-wide n tile, col' = 2*(n&15) + ((n>>4)&1).
// q16 pre-scaled by 1/16.
__global__ __launch_bounds__(256) void qkv_lds(
    const f16* __restrict__ xT,
    const float* __restrict__ Wq, const float* __restrict__ Wk,
    const float* __restrict__ Wv,
    const float* __restrict__ bq, const float* __restrict__ bk,
    const float* __restrict__ bv,
    f16* __restrict__ q16, f16* __restrict__ k16, f16* __restrict__ vT16)
{
  const int nt = blockIdx.x, ctb = blockIdx.y, z = blockIdx.z;
  const int b = z / 3, mat = z % 3;
  const float* W    = (mat == 0) ? Wq : (mat == 1) ? Wk : Wv;
  const float* bias = (mat == 0) ? bq : (mat == 1) ? bk : bv;
  const int n0 = nt * 128, c0 = ctb * 64;

  __shared__ f16 As[128 * 64];
  __shared__ f16 Bs[64 * 64];

  const int t = threadIdx.x, w = t >> 6, lane = t & 63;
  const int c = lane & 15, g = lane >> 4;

  // staging coords: row r, chunk slot d (8 f16 per chunk), phys chunk = d^(r&7)
  const int rB0 = t >> 3, dS = t & 7;       // rows 0..31  (B), also A u=0
  const int rB1 = rB0 + 32;                 // rows 32..63 (B), also A u=1
  const f16* aSrc[4];
  #pragma unroll
  for (int u = 0; u < 4; ++u) {
    const int r = rB0 + 32 * u;
    aSrc[u] = xT + (size_t)(b * N_ + n0 + r) * C_ + 8 * (dS ^ (r & 7));
  }
  const float* wSrc0 = W + (size_t)(c0 + rB0) * C_ + 8 * (dS ^ (rB0 & 7));
  const float* wSrc1 = W + (size_t)(c0 + rB1) * C_ + 8 * (dS ^ (rB1 & 7));

  f32x4 acc[2][4] = {};
  #pragma unroll 1
  for (int k0 = 0; k0 < C_; k0 += 64) {
    // ---- stage A (f16 direct), 128 rows ----
    #pragma unroll
    for (int u = 0; u < 4; ++u)
      *(f16x8*)&As[(rB0 + 32 * u) * 64 + 8 * dS] = *(const f16x8*)(aSrc[u] + k0);
    // ---- stage B (fp32 -> f16), 64 rows ----
    {
      float4 u0 = *(const float4*)(wSrc0 + k0);
      float4 u1 = *(const float4*)(wSrc0 + k0 + 4);
      union { f16x8 v8; f16x2 v2[4]; } u;
      u.v2[0] = cvt_pk(u0.x, u0.y); u.v2[1] = cvt_pk(u0.z, u0.w);
      u.v2[2] = cvt_pk(u1.x, u1.y); u.v2[3] = cvt_pk(u1.z, u1.w);
      *(f16x8*)&Bs[rB0 * 64 + 8 * dS] = u.v8;
    }
    {
      float4 u0 = *(const float4*)(wSrc1 + k0);
      float4 u1 = *(const float4*)(wSrc1 + k0 + 4);
      union { f16x8 v8; f16x2 v2[4]; } u;
      u.v2[0] = cvt_pk(u0.x, u0.y); u.v2[1] = cvt_pk(u0.z, u0.w);
      u.v2[2] = cvt_pk(u1.x, u1.y); u.v2[3] = cvt_pk(u1.z, u1.w);
      *(f16x8*)&Bs[rB1 * 64 + 8 * dS] = u.v8;
    }
    __syncthreads();
    // ---- compute: wave w owns rows [32w, 32w+32) ----
    const int ar0 = 32 * w + c, ar1 = ar0 + 16;
    f16x8 a00 = *(const f16x8*)&As[ar0 * 64 + 8 * (g ^ (ar0 & 7))];
    f16x8 a01 = *(const f16x8*)&As[ar0 * 64 + 8 * ((4 + g) ^ (ar0 & 7))];
    f16x8 a10 = *(const f16x8*)&As[ar1 * 64 + 8 * (g ^ (ar1 & 7))];
    f16x8 a11 = *(const f16x8*)&As[ar1 * 64 + 8 * ((4 + g) ^ (ar1 & 7))];
    #pragma unroll
    for (int ct = 0; ct < 4; ++ct) {
      const int br = ct * 16 + c;
      f16x8 b0 = *(const f16x8*)&Bs[br * 64 + 8 * (g ^ (br & 7))];
      f16x8 b1 = *(const f16x8*)&Bs[br * 64 + 8 * ((4 + g) ^ (br & 7))];
      acc[0][ct] = MFMA16(a00, b0, acc[0][ct]);
      acc[0][ct] = MFMA16(a01, b1, acc[0][ct]);
      acc[1][ct] = MFMA16(a10, b0, acc[1][ct]);
      acc[1][ct] = MFMA16(a11, b1, acc[1][ct]);
    }
    __syncthreads();
  }

  // ---- epilogue ----
  #pragma unroll
  for (int rf = 0; rf < 2; ++rf) {
    const int nOut = n0 + 32 * w + 16 * rf + 4 * g;      // + e
    #pragma unroll
    for (int ct = 0; ct < 4; ++ct) {
      const int ccol = c0 + ct * 16 + c;
      const float bb = bias[ccol];
      if (mat == 2) {
        // PI-order: r = 16rf+4g+e -> col' = 8g + 2e + rf within 32-tile
        const int base = n0 + 32 * w;
        f16* vrow = vT16 + ((size_t)(b * C_ + ccol)) * N_ + base + 8 * g + rf;
        #pragma unroll
        for (int e = 0; e < 4; ++e)
          vrow[2 * e] = (f16)(acc[rf][ct][e] + bb);
      } else {
        const int h = ccol >> 6, d = ccol & 63;
        f16* out = (mat == 0) ? q16 : k16;
        const float sc = (mat == 0) ? 0.0625f : 1.0f;
        #pragma unroll
        for (int e = 0; e < 4; ++e)
          out[((size_t)((b * H_ + h) * N_ + nOut + e)) * DK_ + d] =
              (f16)((acc[rf][ct][e] + bb) * sc);
      }
    }
  }
}

// ---------------- attn: energy(MFMA) + packed-f16 Newton entmax1.5 + PV -------
// 16 q-rows/block, 4 waves x 512-j strips. z kept as 64 f16x2 regs (j, j+16).
// PV in 4 phases, p_lds = 16x520 (PI-paired cols) -> ~17.7 KB LDS, 8 blocks/CU.
__global__ __launch_bounds__(256, 4) void attn(
    const f16* __restrict__ q16, const f16* __restrict__ k16,
    const f16* __restrict__ vT16, float* __restrict__ o)
{
  const int bh = blockIdx.y;
  const int n0 = blockIdx.x * 16;
  const int t = threadIdx.x;
  const int w = t >> 6, lane = t & 63;
  const int c = lane & 15, g = lane >> 4;

  __shared__ f16 p_lds[16 * 520];         // [row][j-quarter, PI-paired], pad 8
  __shared__ float red[2][4][16][2];      // dbuf cross-wave scratch

  const f16* Q  = q16  + (size_t)bh * N_ * DK_;
  const f16* K  = k16  + (size_t)bh * N_ * DK_;
  const f16* VT = vT16 + (size_t)bh * DK_ * N_;

  f16x8 qa0 = *(const f16x8*)(Q + (size_t)(n0 + c) * DK_ + 8 * g);
  f16x8 qa1 = *(const f16x8*)(Q + (size_t)(n0 + c) * DK_ + 32 + 8 * g);

  const int jbase = w * 512;

  // ---- energy -> z2 f16 pairs (z = q.k/16 via pre-scaled q) ----
  f16x2 z2[64];
  #pragma unroll
  for (int tt = 0; tt < 16; ++tt) {
    const f16* kp0 = K + (size_t)(jbase + 32 * tt + c) * DK_ + 8 * g;
    f16x8 kb00 = *(const f16x8*)(kp0);
    f16x8 kb01 = *(const f16x8*)(kp0 + 32);
    f16x8 kb10 = *(const f16x8*)(kp0 + 16 * DK_);
    f16x8 kb11 = *(const f16x8*)(kp0 + 16 * DK_ + 32);
    f32x4 a0 = {}, a1 = {};
    a0 = MFMA16(qa0, kb00, a0);
    a0 = MFMA16(qa1, kb01, a0);
    a1 = MFMA16(qa0, kb10, a1);
    a1 = MFMA16(qa1, kb11, a1);
    #pragma unroll
    for (int e = 0; e < 4; ++e)
      z2[tt * 4 + e] = cvt_pk(a0[e], a1[e]);
  }

  // ---- row max ----
  f16x2 m2[4];
  #pragma unroll
  for (int e = 0; e < 4; ++e) m2[e] = z2[e];
  #pragma unroll
  for (int tt = 1; tt < 16; ++tt)
    #pragma unroll
    for (int e = 0; e < 4; ++e)
      m2[e] = __builtin_elementwise_max(m2[e], z2[tt * 4 + e]);
  float m[4];
  #pragma unroll
  for (int e = 0; e < 4; ++e) m[e] = fmaxf((float)m2[e][0], (float)m2[e][1]);
  #pragma unroll
  for (int dm = 1; dm <= 8; dm <<= 1)
    #pragma unroll
    for (int e = 0; e < 4; ++e) m[e] = fmaxf(m[e], __shfl_xor(m[e], dm, 64));
  if (c == 0) {
    #pragma unroll
    for (int e = 0; e < 4; ++e) red[0][w][4 * g + e][0] = m[e];
  }
  __syncthreads();
  #pragma unroll
  for (int e = 0; e < 4; ++e) {
    const int r = 4 * g + e;
    m[e] = fmaxf(fmaxf(red[0][0][r][0], red[0][1][r][0]),
                 fmaxf(red[0][2][r][0], red[0][3][r][0]));
  }

  float tau[4];
  #pragma unroll
  for (int e = 0; e < 4; ++e) tau[e] = m[e] - 1.f;

  const f16x2 one2  = {(_Float16)1.f, (_Float16)1.f};
  const f16x2 zero2 = {(_Float16)0.f, (_Float16)0.f};

  // ---- Newton on f(tau)=sum clip(z-tau,0)^2 - 1 (packed f16, dot2 accum) ----
  #pragma unroll 1
  for (int it = 0; it < NIT; ++it) {
    const int pb = (it + 1) & 1;
    f16x2 tau2[4];
    #pragma unroll
    for (int e = 0; e < 4; ++e)
      tau2[e] = cvt_pk(tau[e], tau[e]);
    float S1[4] = {0.f, 0.f, 0.f, 0.f}, S2[4] = {0.f, 0.f, 0.f, 0.f};
    #pragma unroll
    for (int tt = 0; tt < 16; ++tt)
      #pragma unroll
      for (int e = 0; e < 4; ++e) {
        f16x2 d2 = z2[tt * 4 + e] - tau2[e];
        d2 = __builtin_elementwise_max(d2, zero2);
        S1[e] = FDOT2(d2, one2, S1[e]);
        S2[e] = FDOT2(d2, d2, S2[e]);
      }
    #pragma unroll
    for (int dm = 1; dm <= 8; dm <<= 1)
      #pragma unroll
      for (int e = 0; e < 4; ++e) {
        S1[e] += __shfl_xor(S1[e], dm, 64);
        S2[e] += __shfl_xor(S2[e], dm, 64);
      }
    if (c == 0) {
      #pragma unroll
      for (int e = 0; e < 4; ++e) {
        red[pb][w][4 * g + e][0] = S1[e];
        red[pb][w][4 * g + e][1] = S2[e];
      }
    }
    __syncthreads();
    #pragma unroll
    for (int e = 0; e < 4; ++e) {
      const int r = 4 * g + e;
      float s1 = red[pb][0][r][0] + red[pb][1][r][0] + red[pb][2][r][0] + red[pb][3][r][0];
      float s2 = red[pb][0][r][1] + red[pb][1][r][1] + red[pb][2][r][1] + red[pb][3][r][1];
      tau[e] = fminf(tau[e] + (s2 - 1.f) / (2.f * s1 + 1e-20f), m[e] - 0.01f);
    }
  }

  // ---- final p = clip(z-tau,0)^2, reuse z2 regs ----
  {
    f16x2 tau2[4];
    #pragma unroll
    for (int e = 0; e < 4; ++e)
      tau2[e] = cvt_pk(tau[e], tau[e]);
    #pragma unroll
    for (int tt = 0; tt < 16; ++tt)
      #pragma unroll
      for (int e = 0; e < 4; ++e) {
        f16x2 d2 = z2[tt * 4 + e] - tau2[e];
        d2 = __builtin_elementwise_max(d2, zero2);
        z2[tt * 4 + e] = d2 * d2;
      }
  }

  // ---- PV in 4 phases: phase q = wave q publishes its strip (PI-paired) ----
  f32x4 oacc = {};
  #pragma unroll 1
  for (int q = 0; q < 4; ++q) {
    if (w == q) {
      #pragma unroll
      for (int tt = 0; tt < 16; ++tt)
        #pragma unroll
        for (int e = 0; e < 4; ++e) {
          const int row = 4 * g + e;
          *(f16x2*)&p_lds[row * 520 + 32 * tt + 2 * c] = z2[tt * 4 + e];
        }
    }
    __syncthreads();
    #pragma unroll
    for (int T = 0; T < 16; ++T) {
      f16x8 pa = *(f16x8*)&p_lds[c * 520 + 32 * T + 8 * g];
      f16x8 vb = *(const f16x8*)(VT + (size_t)(16 * w + c) * N_ + 512 * q + 32 * T + 8 * g);
      oacc = MFMA16(pa, vb, oacc);
    }
    __syncthreads();
  }

  const int b = bh >> 3, h = bh & 7;
  #pragma unroll
  for (int e = 0; e < 4; ++e)
    o[((size_t)b * N_ + n0 + 4 * g + e) * C_ + h * 64 + 16 * w + c] = oacc[e];
}

// ---------------- ln_res: LayerNorm(o)+residual, LDS-transposed x -------------
__global__ __launch_bounds__(256) void ln_res(
    const float* __restrict__ o, const float* __restrict__ x,
    const float* __restrict__ a2, const float* __restrict__ b2,
    float* __restrict__ out)
{
  const int row0 = blockIdx.x * 8;            // 8 rows per block
  const int b = row0 >> 11, nl = row0 & (N_ - 1);
  const int t = threadIdx.x;
  __shared__ float xres[8][516];
  {
    #pragma unroll
    for (int rep = 0; rep < 2; ++rep) {
      const int cc = t + rep * 256;
      const float* xp = x + ((size_t)(b * C_ + cc)) * N_ + nl;
      float4 u0 = *(const float4*)(xp);
      float4 u1 = *(const float4*)(xp + 4);
      xres[0][cc] = u0.x; xres[1][cc] = u0.y; xres[2][cc] = u0.z; xres[3][cc] = u0.w;
      xres[4][cc] = u1.x; xres[5][cc] = u1.y; xres[6][cc] = u1.z; xres[7][cc] = u1.w;
    }
  }
  __syncthreads();
  const int w = t >> 6, lane = t & 63;
  #pragma unroll
  for (int rr = 0; rr < 2; ++rr) {
    const int r = w * 2 + rr;
    const size_t row = (size_t)row0 + r;
    float v[8];
    #pragma unroll
    for (int i = 0; i < 8; ++i) v[i] = o[row * C_ + lane + 64 * i];
    float s = 0.f, ss = 0.f;
    #pragma unroll
    for (int i = 0; i < 8; ++i) { s += v[i]; ss = fmaf(v[i], v[i], ss); }
    #pragma unroll
    for (int dm = 1; dm <= 32; dm <<= 1) {
      s  += __shfl_xor(s, dm, 64);
      ss += __shfl_xor(ss, dm, 64);
    }
    const float mean = s * (1.f / C_);
    float var = (ss - (float)C_ * mean * mean) * (1.f / (C_ - 1));
    var = fmaxf(var, 0.f);
    const float rd = 1.f / (sqrtf(var) + 1e-6f);
    #pragma unroll
    for (int i = 0; i < 8; ++i) {
      const int cc = lane + 64 * i;
      out[row * C_ + cc] = a2[cc] * (v[i] - mean) * rd + b2[cc] + xres[r][cc];
    }
  }
}

// ---------------- launch ------------------------------------------------------
extern "C" void kernel_launch(void* const* d_in, const int* in_sizes, int n_in,
                              void* d_out, int out_size, void* d_ws, size_t ws_size,
                              hipStream_t stream)
{
  const float* x  = (const float*)d_in[0];
  const float* Wq = (const float*)d_in[1];
  const float* bq = (const float*)d_in[2];
  const float* Wk = (const float*)d_in[3];
  const float* bk = (const float*)d_in[4];
  const float* Wv = (const float*)d_in[5];
  const float* bv = (const float*)d_in[6];
  const float* a2 = (const float*)d_in[7];
  const float* b2 = (const float*)d_in[8];

  const size_t HEADSZ = (size_t)BH_ * N_ * DK_;   // 2,097,152 elems
  f16* q16  = (f16*)d_ws;                         // 4 MB
  f16* k16  = q16 + HEADSZ;                       // 4 MB
  f16* vT16 = k16 + HEADSZ;                       // 4 MB (ws total = 12 MB, proven)

  // xT16 lives in d_out (8 MB): dead before attn overwrites it with o.
  f16* xT16 = (f16*)d_out;                        // 4 MB (B*N*C f16)
  float* o  = (float*)d_out;

  prep_x <<<dim3(32, 8, 2),  256, 0, stream>>>(x, xT16);
  qkv_lds<<<dim3(16, 8, 6),  256, 0, stream>>>(xT16, Wq, Wk, Wv, bq, bk, bv,
                                               q16, k16, vT16);
  attn   <<<dim3(N_ / 16, BH_), 256, 0, stream>>>(q16, k16, vT16, o);
  ln_res <<<dim3(512),       256, 0, stream>>>(o, x, a2, b2, (float*)d_out);
}

// Round 8
// 186.174 us; speedup vs baseline: 1.2448x; 1.2448x over previous
//
#include <hip/hip_runtime.h>

typedef _Float16 f16;
typedef _Float16 f16x2 __attribute__((ext_vector_type(2)));
typedef _Float16 f16x4 __attribute__((ext_vector_type(4)));
typedef _Float16 f16x8 __attribute__((ext_vector_type(8)));
typedef float    f32x4 __attribute__((ext_vector_type(4)));

#define B_  2
#define C_  512
#define N_  2048
#define H_  8
#define DK_ 64
#define BH_ 16
#define NIT 8

static __device__ __forceinline__ f16x2 cvt_pk(float a, float b) {
  return __builtin_bit_cast(f16x2, __builtin_amdgcn_cvt_pkrtz(a, b));
}

#if defined(__has_builtin)
#if __has_builtin(__builtin_amdgcn_fdot2)
#define FDOT2(a,b,c) __builtin_amdgcn_fdot2((a),(b),(c),false)
#endif
#endif
#ifndef FDOT2
static __device__ __forceinline__ float FDOT2(f16x2 a, f16x2 b, float c) {
  return c + (float)a[0]*(float)b[0] + (float)a[1]*(float)b[1];
}
#endif

#define MFMA16(a,b,acc) __builtin_amdgcn_mfma_f32_16x16x32_f16((a),(b),(acc),0,0,0)

// Fragment-linear layouts (1 KB contiguous per wave-load, ptr = base + 8*lane):
//   q16/k16: [bh][jt(128)][kk(2)][lane(64)][8]   elem = X[jt*16 + (lane&15)][kk*32 + 8*(lane>>4) + i]
//   vT16   : [bh][dt(4)][jc(64)][lane(64)][8]    elem = V^T[dt*16 + (lane&15)][32-tile jc, PI-col 8*(lane>>4)+i]
//   PI-col within a 32-wide n-tile: col' = 2*(n&15) + ((n>>4)&1)

// ---------------- prep_x: x (b,m,n) fp32 -> xT16 (b,n,m) f16 ------------------
__global__ __launch_bounds__(256) void prep_x(const float* __restrict__ x,
                                              f16* __restrict__ xT)
{
  const int nt = blockIdx.x, mt = blockIdx.y, b = blockIdx.z;
  const int n0 = nt * 64, m0 = mt * 64;
  __shared__ float tile[64][65];
  const int t = threadIdx.x;
  {
    const int ml = t >> 2, nc = (t & 3) * 16;
    const float* src = x + ((size_t)(b * C_ + m0 + ml)) * N_ + n0 + nc;
    *(float4*)&tile[ml][nc]      = *(const float4*)(src);
    *(float4*)&tile[ml][nc + 4]  = *(const float4*)(src + 4);
    *(float4*)&tile[ml][nc + 8]  = *(const float4*)(src + 8);
    *(float4*)&tile[ml][nc + 12] = *(const float4*)(src + 12);
  }
  __syncthreads();
  {
    const int nl = t >> 2, mc = (t & 3) * 16;
    f16x8 o0, o1;
    #pragma unroll
    for (int i = 0; i < 8; ++i) {
      o0[i] = (f16)tile[mc + i][nl];
      o1[i] = (f16)tile[mc + 8 + i][nl];
    }
    f16* dst = xT + ((size_t)(b * N_ + n0 + nl)) * C_ + m0 + mc;
    *(f16x8*)(dst)     = o0;
    *(f16x8*)(dst + 8) = o1;
  }
}

// ---------------- qkv_lds: LDS-staged GEMM, 128n x 64c tile, BK=64 ------------
// A = xT16 (f16), B = W fp32 (cvt in stager). XOR-swizzled LDS (chunk ^= row&7).
// Outputs in fragment-linear layouts (see top). q16 pre-scaled by 1/16.
__global__ __launch_bounds__(256) void qkv_lds(
    const f16* __restrict__ xT,
    const float* __restrict__ Wq, const float* __restrict__ Wk,
    const float* __restrict__ Wv,
    const float* __restrict__ bq, const float* __restrict__ bk,
    const float* __restrict__ bv,
    f16* __restrict__ q16, f16* __restrict__ k16, f16* __restrict__ vT16)
{
  const int nt = blockIdx.x, ctb = blockIdx.y, z = blockIdx.z;
  const int b = z / 3, mat = z % 3;
  const float* W    = (mat == 0) ? Wq : (mat == 1) ? Wk : Wv;
  const float* bias = (mat == 0) ? bq : (mat == 1) ? bk : bv;
  const int n0 = nt * 128, c0 = ctb * 64;

  __shared__ f16 As[128 * 64];
  __shared__ f16 Bs[64 * 64];

  const int t = threadIdx.x, w = t >> 6, lane = t & 63;
  const int c = lane & 15, g = lane >> 4;

  const int rB0 = t >> 3, dS = t & 7;       // rows 0..31  (B), also A u=0
  const int rB1 = rB0 + 32;                 // rows 32..63 (B)
  const f16* aSrc[4];
  #pragma unroll
  for (int u = 0; u < 4; ++u) {
    const int r = rB0 + 32 * u;
    aSrc[u] = xT + (size_t)(b * N_ + n0 + r) * C_ + 8 * (dS ^ (r & 7));
  }
  const float* wSrc0 = W + (size_t)(c0 + rB0) * C_ + 8 * (dS ^ (rB0 & 7));
  const float* wSrc1 = W + (size_t)(c0 + rB1) * C_ + 8 * (dS ^ (rB1 & 7));

  f32x4 acc[2][4] = {};
  #pragma unroll 1
  for (int k0 = 0; k0 < C_; k0 += 64) {
    #pragma unroll
    for (int u = 0; u < 4; ++u)
      *(f16x8*)&As[(rB0 + 32 * u) * 64 + 8 * dS] = *(const f16x8*)(aSrc[u] + k0);
    {
      float4 u0 = *(const float4*)(wSrc0 + k0);
      float4 u1 = *(const float4*)(wSrc0 + k0 + 4);
      union { f16x8 v8; f16x2 v2[4]; } u;
      u.v2[0] = cvt_pk(u0.x, u0.y); u.v2[1] = cvt_pk(u0.z, u0.w);
      u.v2[2] = cvt_pk(u1.x, u1.y); u.v2[3] = cvt_pk(u1.z, u1.w);
      *(f16x8*)&Bs[rB0 * 64 + 8 * dS] = u.v8;
    }
    {
      float4 u0 = *(const float4*)(wSrc1 + k0);
      float4 u1 = *(const float4*)(wSrc1 + k0 + 4);
      union { f16x8 v8; f16x2 v2[4]; } u;
      u.v2[0] = cvt_pk(u0.x, u0.y); u.v2[1] = cvt_pk(u0.z, u0.w);
      u.v2[2] = cvt_pk(u1.x, u1.y); u.v2[3] = cvt_pk(u1.z, u1.w);
      *(f16x8*)&Bs[rB1 * 64 + 8 * dS] = u.v8;
    }
    __syncthreads();
    const int ar0 = 32 * w + c, ar1 = ar0 + 16;
    f16x8 a00 = *(const f16x8*)&As[ar0 * 64 + 8 * (g ^ (ar0 & 7))];
    f16x8 a01 = *(const f16x8*)&As[ar0 * 64 + 8 * ((4 + g) ^ (ar0 & 7))];
    f16x8 a10 = *(const f16x8*)&As[ar1 * 64 + 8 * (g ^ (ar1 & 7))];
    f16x8 a11 = *(const f16x8*)&As[ar1 * 64 + 8 * ((4 + g) ^ (ar1 & 7))];
    #pragma unroll
    for (int ct = 0; ct < 4; ++ct) {
      const int br = ct * 16 + c;
      f16x8 b0 = *(const f16x8*)&Bs[br * 64 + 8 * (g ^ (br & 7))];
      f16x8 b1 = *(const f16x8*)&Bs[br * 64 + 8 * ((4 + g) ^ (br & 7))];
      acc[0][ct] = MFMA16(a00, b0, acc[0][ct]);
      acc[0][ct] = MFMA16(a01, b1, acc[0][ct]);
      acc[1][ct] = MFMA16(a10, b0, acc[1][ct]);
      acc[1][ct] = MFMA16(a11, b1, acc[1][ct]);
    }
    __syncthreads();
  }

  // ---- epilogue: fragment-linear stores ----
  #pragma unroll
  for (int rf = 0; rf < 2; ++rf) {
    #pragma unroll
    for (int ct = 0; ct < 4; ++ct) {
      const int ccol = c0 + ct * 16 + c;
      const float bb = bias[ccol];
      const int h2 = ccol >> 6;
      const int bh = b * H_ + h2;
      if (mat == 2) {
        // V: dt = (d&63)>>4, c'=d&15; jc = (n0+32w)>>5; PI-col = 8g+2e+rf
        const int dih = ccol & 63, dt = dih >> 4, cp = dih & 15;
        const int jc = (n0 + 32 * w) >> 5;
        f16* vp = vT16 + (((size_t)(bh * 4 + dt)) * 64 + jc) * 512
                       + 128 * g + 8 * cp + rf;
        #pragma unroll
        for (int e = 0; e < 4; ++e)
          vp[2 * e] = (f16)(acc[rf][ct][e] + bb);
      } else {
        // Q/K: jt = (n0+32w+16rf)>>4; row-in-tile = 4g+e; kk = d>>5
        const int d = ccol & 63, kk = d >> 5, gp = (d >> 3) & 3, ii = d & 7;
        const int jt = (n0 + 32 * w + 16 * rf) >> 4;
        f16* out = (mat == 0) ? q16 : k16;
        const float sc = (mat == 0) ? 0.0625f : 1.0f;
        f16* op = out + (((size_t)(bh * 128 + jt)) * 2 + kk) * 512
                      + 128 * gp + 32 * g + ii;
        #pragma unroll
        for (int e = 0; e < 4; ++e)
          op[8 * e] = (f16)((acc[rf][ct][e] + bb) * sc);
      }
    }
  }
}

// ---------------- attn: energy(MFMA) + packed-f16 Newton entmax1.5 + PV -------
// Flat grid 2048: bh = id&15 (head->XCD affinity), nt = id>>4.
// All operand loads are contiguous 1 KB per wave (frag-linear layouts).
__global__ __launch_bounds__(256, 4) void attn(
    const f16* __restrict__ q16, const f16* __restrict__ k16,
    const f16* __restrict__ vT16, float* __restrict__ o)
{
  const int id = blockIdx.x;
  const int bh = id & 15;
  const int n0 = (id >> 4) * 16;
  const int t = threadIdx.x;
  const int w = t >> 6, lane = t & 63;
  const int c = lane & 15, g = lane >> 4;

  __shared__ f16 p_lds[16 * 520];         // [row][j-quarter, PI-paired], pad 8
  __shared__ float red[2][4][16][2];      // dbuf cross-wave scratch

  const f16* Qb = q16  + (size_t)bh * (128 * 2 * 512);
  const f16* Kb = k16  + (size_t)bh * (128 * 2 * 512);
  const f16* Vb = vT16 + (size_t)bh * (4 * 64 * 512);

  const f16* qp = Qb + (size_t)(n0 >> 4) * 1024 + 8 * lane;
  f16x8 qa0 = *(const f16x8*)(qp);
  f16x8 qa1 = *(const f16x8*)(qp + 512);

  // ---- energy -> z2 f16 pairs (z = q.k/16 via pre-scaled q) ----
  f16x2 z2[64];
  #pragma unroll
  for (int tt = 0; tt < 16; ++tt) {
    const f16* kp = Kb + (size_t)(32 * w + 2 * tt) * 1024 + 8 * lane;
    f16x8 kb00 = *(const f16x8*)(kp);
    f16x8 kb01 = *(const f16x8*)(kp + 512);
    f16x8 kb10 = *(const f16x8*)(kp + 1024);
    f16x8 kb11 = *(const f16x8*)(kp + 1536);
    f32x4 a0 = {}, a1 = {};
    a0 = MFMA16(qa0, kb00, a0);
    a0 = MFMA16(qa1, kb01, a0);
    a1 = MFMA16(qa0, kb10, a1);
    a1 = MFMA16(qa1, kb11, a1);
    #pragma unroll
    for (int e = 0; e < 4; ++e)
      z2[tt * 4 + e] = cvt_pk(a0[e], a1[e]);
  }

  // ---- row max ----
  f16x2 m2[4];
  #pragma unroll
  for (int e = 0; e < 4; ++e) m2[e] = z2[e];
  #pragma unroll
  for (int tt = 1; tt < 16; ++tt)
    #pragma unroll
    for (int e = 0; e < 4; ++e)
      m2[e] = __builtin_elementwise_max(m2[e], z2[tt * 4 + e]);
  float m[4];
  #pragma unroll
  for (int e = 0; e < 4; ++e) m[e] = fmaxf((float)m2[e][0], (float)m2[e][1]);
  #pragma unroll
  for (int dm = 1; dm <= 8; dm <<= 1)
    #pragma unroll
    for (int e = 0; e < 4; ++e) m[e] = fmaxf(m[e], __shfl_xor(m[e], dm, 64));
  if (c == 0) {
    #pragma unroll
    for (int e = 0; e < 4; ++e) red[0][w][4 * g + e][0] = m[e];
  }
  __syncthreads();
  #pragma unroll
  for (int e = 0; e < 4; ++e) {
    const int r = 4 * g + e;
    m[e] = fmaxf(fmaxf(red[0][0][r][0], red[0][1][r][0]),
                 fmaxf(red[0][2][r][0], red[0][3][r][0]));
  }

  float tau[4];
  #pragma unroll
  for (int e = 0; e < 4; ++e) tau[e] = m[e] - 1.f;

  const f16x2 one2  = {(_Float16)1.f, (_Float16)1.f};
  const f16x2 zero2 = {(_Float16)0.f, (_Float16)0.f};

  // ---- Newton on f(tau)=sum clip(z-tau,0)^2 - 1 (packed f16, dot2 accum) ----
  #pragma unroll 1
  for (int it = 0; it < NIT; ++it) {
    const int pb = (it + 1) & 1;
    f16x2 tau2[4];
    #pragma unroll
    for (int e = 0; e < 4; ++e)
      tau2[e] = cvt_pk(tau[e], tau[e]);
    float S1[4] = {0.f, 0.f, 0.f, 0.f}, S2[4] = {0.f, 0.f, 0.f, 0.f};
    #pragma unroll
    for (int tt = 0; tt < 16; ++tt)
      #pragma unroll
      for (int e = 0; e < 4; ++e) {
        f16x2 d2 = z2[tt * 4 + e] - tau2[e];
        d2 = __builtin_elementwise_max(d2, zero2);
        S1[e] = FDOT2(d2, one2, S1[e]);
        S2[e] = FDOT2(d2, d2, S2[e]);
      }
    #pragma unroll
    for (int dm = 1; dm <= 8; dm <<= 1)
      #pragma unroll
      for (int e = 0; e < 4; ++e) {
        S1[e] += __shfl_xor(S1[e], dm, 64);
        S2[e] += __shfl_xor(S2[e], dm, 64);
      }
    if (c == 0) {
      #pragma unroll
      for (int e = 0; e < 4; ++e) {
        red[pb][w][4 * g + e][0] = S1[e];
        red[pb][w][4 * g + e][1] = S2[e];
      }
    }
    __syncthreads();
    #pragma unroll
    for (int e = 0; e < 4; ++e) {
      const int r = 4 * g + e;
      float s1 = red[pb][0][r][0] + red[pb][1][r][0] + red[pb][2][r][0] + red[pb][3][r][0];
      float s2 = red[pb][0][r][1] + red[pb][1][r][1] + red[pb][2][r][1] + red[pb][3][r][1];
      tau[e] = fminf(tau[e] + (s2 - 1.f) / (2.f * s1 + 1e-20f), m[e] - 0.01f);
    }
  }

  // ---- final p = clip(z-tau,0)^2, reuse z2 regs ----
  {
    f16x2 tau2[4];
    #pragma unroll
    for (int e = 0; e < 4; ++e)
      tau2[e] = cvt_pk(tau[e], tau[e]);
    #pragma unroll
    for (int tt = 0; tt < 16; ++tt)
      #pragma unroll
      for (int e = 0; e < 4; ++e) {
        f16x2 d2 = z2[tt * 4 + e] - tau2[e];
        d2 = __builtin_elementwise_max(d2, zero2);
        z2[tt * 4 + e] = d2 * d2;
      }
  }

  // ---- PV in 4 phases: phase q = wave q publishes its strip (PI-paired) ----
  f32x4 oacc = {};
  #pragma unroll 1
  for (int q = 0; q < 4; ++q) {
    if (w == q) {
      #pragma unroll
      for (int tt = 0; tt < 16; ++tt)
        #pragma unroll
        for (int e = 0; e < 4; ++e) {
          const int row = 4 * g + e;
          *(f16x2*)&p_lds[row * 520 + 32 * tt + 2 * c] = z2[tt * 4 + e];
        }
    }
    __syncthreads();
    #pragma unroll
    for (int T = 0; T < 16; ++T) {
      f16x8 pa = *(f16x8*)&p_lds[c * 520 + 32 * T + 8 * g];
      f16x8 vb = *(const f16x8*)(Vb + ((size_t)w * 64 + 16 * q + T) * 512 + 8 * lane);
      oacc = MFMA16(pa, vb, oacc);
    }
    __syncthreads();
  }

  const int b = bh >> 3, h = bh & 7;
  #pragma unroll
  for (int e = 0; e < 4; ++e)
    o[((size_t)b * N_ + n0 + 4 * g + e) * C_ + h * 64 + 16 * w + c] = oacc[e];
}

// ---------------- ln_res: LayerNorm(o)+residual, LDS-transposed x -------------
__global__ __launch_bounds__(256) void ln_res(
    const float* __restrict__ o, const float* __restrict__ x,
    const float* __restrict__ a2, const float* __restrict__ b2,
    float* __restrict__ out)
{
  const int row0 = blockIdx.x * 8;            // 8 rows per block
  const int b = row0 >> 11, nl = row0 & (N_ - 1);
  const int t = threadIdx.x;
  __shared__ float xres[8][516];
  {
    #pragma unroll
    for (int rep = 0; rep < 2; ++rep) {
      const int cc = t + rep * 256;
      const float* xp = x + ((size_t)(b * C_ + cc)) * N_ + nl;
      float4 u0 = *(const float4*)(xp);
      float4 u1 = *(const float4*)(xp + 4);
      xres[0][cc] = u0.x; xres[1][cc] = u0.y; xres[2][cc] = u0.z; xres[3][cc] = u0.w;
      xres[4][cc] = u1.x; xres[5][cc] = u1.y; xres[6][cc] = u1.z; xres[7][cc] = u1.w;
    }
  }
  __syncthreads();
  const int w = t >> 6, lane = t & 63;
  #pragma unroll
  for (int rr = 0; rr < 2; ++rr) {
    const int r = w * 2 + rr;
    const size_t row = (size_t)row0 + r;
    float v[8];
    #pragma unroll
    for (int i = 0; i < 8; ++i) v[i] = o[row * C_ + lane + 64 * i];
    float s = 0.f, ss = 0.f;
    #pragma unroll
    for (int i = 0; i < 8; ++i) { s += v[i]; ss = fmaf(v[i], v[i], ss); }
    #pragma unroll
    for (int dm = 1; dm <= 32; dm <<= 1) {
      s  += __shfl_xor(s, dm, 64);
      ss += __shfl_xor(ss, dm, 64);
    }
    const float mean = s * (1.f / C_);
    float var = (ss - (float)C_ * mean * mean) * (1.f / (C_ - 1));
    var = fmaxf(var, 0.f);
    const float rd = 1.f / (sqrtf(var) + 1e-6f);
    #pragma unroll
    for (int i = 0; i < 8; ++i) {
      const int cc = lane + 64 * i;
      out[row * C_ + cc] = a2[cc] * (v[i] - mean) * rd + b2[cc] + xres[r][cc];
    }
  }
}

// ---------------- launch ------------------------------------------------------
extern "C" void kernel_launch(void* const* d_in, const int* in_sizes, int n_in,
                              void* d_out, int out_size, void* d_ws, size_t ws_size,
                              hipStream_t stream)
{
  const float* x  = (const float*)d_in[0];
  const float* Wq = (const float*)d_in[1];
  const float* bq = (const float*)d_in[2];
  const float* Wk = (const float*)d_in[3];
  const float* bk = (const float*)d_in[4];
  const float* Wv = (const float*)d_in[5];
  const float* bv = (const float*)d_in[6];
  const float* a2 = (const float*)d_in[7];
  const float* b2 = (const float*)d_in[8];

  const size_t HEADSZ = (size_t)BH_ * N_ * DK_;   // 2,097,152 elems
  f16* q16  = (f16*)d_ws;                         // 4 MB
  f16* k16  = q16 + HEADSZ;                       // 4 MB
  f16* vT16 = k16 + HEADSZ;                       // 4 MB (ws total = 12 MB, proven)

  // xT16 lives in d_out (8 MB): dead before attn overwrites it with o.
  f16* xT16 = (f16*)d_out;                        // 4 MB (B*N*C f16)
  float* o  = (float*)d_out;

  prep_x <<<dim3(32, 8, 2),  256, 0, stream>>>(x, xT16);
  qkv_lds<<<dim3(16, 8, 6),  256, 0, stream>>>(xT16, Wq, Wk, Wv, bq, bk, bv,
                                               q16, k16, vT16);
  attn   <<<dim3(2048),      256, 0, stream>>>(q16, k16, vT16, o);
  ln_res <<<dim3(512),       256, 0, stream>>>(o, x, a2, b2, (float*)d_out);
}